// Round 16
// baseline (263.284 us; speedup 1.0000x reference)
//
#include <hip/hip_runtime.h>
#include <cstdint>

#define NN 8192
#define NT 16384         // 2 batches merged: total rows
#define EE 131072
#define EPAD (EE + NN)   // edges + self loops = 139264
#define SPAD (EPAD + 3 * NN)  // 4-aligned padded CSR capacity
#define FIN 128
#define CH 512           // H*HID = H*OUT
#define NH 8
#define NEG 0.2f

typedef __attribute__((ext_vector_type(8))) short short8;
typedef __attribute__((ext_vector_type(4))) unsigned short u16x4;
typedef __attribute__((ext_vector_type(4))) float f32x4;
typedef __attribute__((ext_vector_type(4))) int i32x4;

__device__ inline unsigned short bf16rne(float x) {
    unsigned u = __float_as_uint(x);
    unsigned r = (u + 0x7FFFu + ((u >> 16) & 1u)) >> 16;
    return (unsigned short)r;
}
__device__ inline float bf16tof(unsigned short h) {
    return __uint_as_float((unsigned)h << 16);
}
__device__ inline void gload16(const void* g, void* l) {
    __builtin_amdgcn_global_load_lds((const __attribute__((address_space(1))) void*)g,
                                     (__attribute__((address_space(3))) void*)l, 16, 0, 0);
}
// cross-lane add via DPP (VALU only, no DS crossbar). CTRL: 0xB1=quad_perm
// xor1, 0x4E=quad_perm xor2, 0x124=row_ror:4, 0x128=row_ror:8.
template <int CTRL>
__device__ inline float dpp_add(float x) {
    int v = __builtin_amdgcn_update_dpp(0, __float_as_int(x), CTRL, 0xF, 0xF, true);
    return x + __int_as_float(v);
}

// ---------- CSR build (4-aligned padded segments) ----------

__global__ __launch_bounds__(256) void k_deg(const int* __restrict__ ei, int* __restrict__ deg) {
    int e = blockIdx.x * 256 + threadIdx.x;
    if (e >= EPAD) return;
    int dst = (e < EE) ? ei[EE + e] : (e - EE);
    atomicAdd(&deg[dst], 1);
}

__global__ __launch_bounds__(1024) void k_scan(const int* __restrict__ deg, int* __restrict__ rowptr) {
    __shared__ int part[1024];
    int t = threadIdx.x;
    int loc[8];
    int s = 0;
#pragma unroll
    for (int i = 0; i < 8; i++) { loc[i] = s; s += (deg[t * 8 + i] + 3) & ~3; }
    part[t] = s;
    __syncthreads();
    if (t == 0) {
        int run = 0;
        for (int i = 0; i < 1024; i++) { int tmp = part[i]; part[i] = run; run += tmp; }
        rowptr[NN] = run;
    }
    __syncthreads();
    int base = part[t];
#pragma unroll
    for (int i = 0; i < 8; i++) rowptr[t * 8 + i] = base + loc[i];
}

__global__ __launch_bounds__(256) void k_scatter(const int* __restrict__ ei, const int* __restrict__ rowptr,
                                                 int* __restrict__ cursor, int* __restrict__ ssrc) {
    int e = blockIdx.x * 256 + threadIdx.x;
    if (e >= EPAD) return;
    int src = (e < EE) ? ei[e] : (e - EE);
    int dst = (e < EE) ? ei[EE + e] : (e - EE);
    int pos = rowptr[dst] + atomicAdd(&cursor[dst], 1);
    ssrc[pos] = src;
}

// fill pad slots with src=0 (row 0 gather, masked out of softmax)
__global__ __launch_bounds__(256) void k_pad(const int* __restrict__ rowptr, const int* __restrict__ deg,
                                             int* __restrict__ ssrc) {
    int n = blockIdx.x * 256 + threadIdx.x;
    if (n >= NN) return;
    int e = rowptr[n] + deg[n], pe = rowptr[n + 1];
    for (int i = e; i < pe; i++) ssrc[i] = 0;
}

// ---------- degree-descending node order (counting sort; tail reduction) ----------

__global__ __launch_bounds__(256) void k_hist(const int* __restrict__ deg, int* __restrict__ hist) {
    int n = blockIdx.x * 256 + threadIdx.x;
    if (n >= NN) return;
    atomicAdd(&hist[min(deg[n], 255)], 1);
}

// turn hist into DESCENDING-degree exclusive offsets (doubles as scatter cursor)
__global__ __launch_bounds__(64) void k_binscan(int* __restrict__ hist) {
    if (threadIdx.x == 0) {
        int run = 0;
        for (int b = 255; b >= 0; b--) { int t = hist[b]; hist[b] = run; run += t; }
    }
}

__global__ __launch_bounds__(256) void k_order(const int* __restrict__ deg, int* __restrict__ hist,
                                               int* __restrict__ order) {
    int n = blockIdx.x * 256 + threadIdx.x;
    if (n >= NN) return;
    int pos = atomicAdd(&hist[min(deg[n], 255)], 1);
    order[pos] = n;
}

// ---------- conversions ----------

__global__ __launch_bounds__(256) void k_cvt_ah(const float* __restrict__ F,
                                                unsigned short* __restrict__ Ah, int n4) {
    int i = blockIdx.x * 256 + threadIdx.x;
    if (i >= n4) return;
    f32x4 v = ((const f32x4*)F)[i];
#pragma unroll
    for (int c = 0; c < 4; c++) Ah[i * 4 + c] = bf16rne(v[c]);
}

// W[K][512] (Wl,Wr) -> Wt[n=1024][K] hi/lo (transposed, K contiguous)
template <int K>
__global__ __launch_bounds__(256) void k_cvt_w(const float* __restrict__ Wl, const float* __restrict__ Wr,
                                               unsigned short* __restrict__ Wh, unsigned short* __restrict__ Wlo) {
    int idx = blockIdx.x * 256 + threadIdx.x;   // = n*K + k
    int n = idx / K, k = idx % K;
    const float* W = (n < 512) ? Wl : Wr;
    float x = W[k * 512 + (n & 511)];
    unsigned short h = bf16rne(x);
    Wh[idx] = h;
    Wlo[idx] = bf16rne(x - bf16tof(h));
}

// ---------- split-bf16 MFMA GEMM: [NT x K] @ [K x 1024] -> XLb (bf16) | XR (f32) ----------
// A in bf16-hi. USE_BL=1: B in hi+lo (2 MFMA/frag, ~fp32-accurate B).
// USE_BL=0: B hi only (layer 2; error budget allows). Single-buffer m97 loop.

template <int K, int USE_BL>
__global__ __launch_bounds__(256) void k_gemm_mfma(const unsigned short* __restrict__ Ah,
                                                   const unsigned short* __restrict__ Bh,
                                                   const unsigned short* __restrict__ Bl,
                                                   unsigned short* __restrict__ XLb,
                                                   float* __restrict__ XR) {
    __shared__ unsigned short sAh[4][128][8], sBh[4][128][8];
    __shared__ unsigned short sBl[USE_BL ? 4 : 1][128][8];
    int tid = threadIdx.x;
    int l = tid & 63;
    int w = tid >> 6, wm = w >> 1, wn = w & 1;
    int m0 = blockIdx.x * 128, n0 = blockIdx.y * 128;
    int lr = l & 15, kh = l >> 4;
    f32x4 acc[4][4] = {};

    for (int k0 = 0; k0 < K; k0 += 32) {
#pragma unroll
        for (int g = 0; g < 2; g++) {
            int cell = g * 256 + tid;
            int ckh = cell >> 7, cr = cell & 127;
            int ka = k0 + ckh * 8;
            gload16(Ah + (size_t)(m0 + cr) * K + ka, &sAh[ckh][cr][0]);
            gload16(Bh + (size_t)(n0 + cr) * K + ka, &sBh[ckh][cr][0]);
            if (USE_BL) gload16(Bl + (size_t)(n0 + cr) * K + ka, &sBl[ckh][cr][0]);
        }
        __syncthreads();
        short8 fah[4], fbh[4], fbl[4];
#pragma unroll
        for (int i = 0; i < 4; i++) {
            fah[i] = *(const short8*)&sAh[kh][wm * 64 + i * 16 + lr][0];
            fbh[i] = *(const short8*)&sBh[kh][wn * 64 + i * 16 + lr][0];
            if (USE_BL) fbl[i] = *(const short8*)&sBl[kh][wn * 64 + i * 16 + lr][0];
        }
#pragma unroll
        for (int i = 0; i < 4; i++)
#pragma unroll
            for (int j = 0; j < 4; j++) {
                if (USE_BL)
                    acc[i][j] = __builtin_amdgcn_mfma_f32_16x16x32_bf16(fah[i], fbl[j], acc[i][j], 0, 0, 0);
                acc[i][j] = __builtin_amdgcn_mfma_f32_16x16x32_bf16(fah[i], fbh[j], acc[i][j], 0, 0, 0);
            }
        __syncthreads();
    }
    // C/D layout: col = lane&15, row = (lane>>4)*4 + q  [m89-verified]
    int colt = n0 + wn * 64;     // wave-uniform
    int cb = colt & 511;
    if (colt < 512) {
#pragma unroll
        for (int i = 0; i < 4; i++) {
            int mg = m0 + wm * 64 + i * 16 + kh * 4;
#pragma unroll
            for (int j = 0; j < 4; j++) {
                int cg = cb + j * 16 + lr;
#pragma unroll
                for (int q = 0; q < 4; q++)
                    XLb[(size_t)(mg + q) * CH + cg] = bf16rne(acc[i][j][q]);
            }
        }
    } else {
#pragma unroll
        for (int i = 0; i < 4; i++) {
            int mg = m0 + wm * 64 + i * 16 + kh * 4;
#pragma unroll
            for (int j = 0; j < 4; j++) {
                int cg = cb + j * 16 + lr;
#pragma unroll
                for (int q = 0; q < 4; q++)
                    XR[(size_t)(mg + q) * CH + cg] = acc[i][j][q];
            }
        }
    }
}

// ---------- fused per-node: logits + online softmax + aggregation ----------
// ONE node-instance per 128-thread block: blockIdx -> (sorted node, batch).
// Degree-descending order: long nodes first, short nodes backfill the tail.
// 2 waves per block (head-group g); lane l owns 4 consecutive channels
// g*256+l*4 (one head). 3-deep pipeline over 4-edge chunks (idx int4 +
// gathers in flight). Single bf16->f32 convert per value; lrelu =
// max(t, 0.2t). DPP-only fold; per-lane softmax state; defer-rescale THR=8.
// Tail/pad edges masked via z=-1e30 (pads gather row 0, always valid).

#define GATHER(CX, IV)                                                         \
  {                                                                            \
    CX[0] = *(const u16x4*)(XLg + (size_t)IV[0] * CH);                         \
    CX[1] = *(const u16x4*)(XLg + (size_t)IV[1] * CH);                         \
    CX[2] = *(const u16x4*)(XLg + (size_t)IV[2] * CH);                         \
    CX[3] = *(const u16x4*)(XLg + (size_t)IV[3] * CH);                         \
  }

#define PROCESS(CX, cb)                                                        \
  {                                                                            \
    float f[4][4];                                                             \
    _Pragma("unroll") for (int e = 0; e < 4; e++)                              \
      _Pragma("unroll") for (int r = 0; r < 4; r++)                            \
        f[e][r] = bf16tof(CX[e][r]);                                           \
    float z[4];                                                                \
    _Pragma("unroll") for (int e = 0; e < 4; e++) {                            \
      float s = 0.f;                                                           \
      _Pragma("unroll") for (int r = 0; r < 4; r++) {                          \
        float t = f[e][r] + xrv[r];                                            \
        t = fmaxf(t, NEG * t);                                                 \
        s += t * atv[r];                                                       \
      }                                                                        \
      z[e] = s;                                                                \
    }                                                                          \
    _Pragma("unroll") for (int e = 0; e < 4; e++) {                            \
      z[e] = dpp_add<0xB1>(z[e]);                                              \
      z[e] = dpp_add<0x4E>(z[e]);                                              \
      z[e] = dpp_add<0x124>(z[e]);                                             \
      z[e] = dpp_add<0x128>(z[e]);                                             \
    }                                                                          \
    _Pragma("unroll") for (int e = 1; e < 4; e++)                              \
      if ((cb) + e >= end) z[e] = -1e30f;                                      \
    float mc = fmaxf(fmaxf(z[0], z[1]), fmaxf(z[2], z[3]));                    \
    if (__ballot(mc > mh + 8.f) == 0ULL) {                                     \
      float p0 = __expf(z[0] - mh), p1 = __expf(z[1] - mh);                    \
      float p2 = __expf(z[2] - mh), p3 = __expf(z[3] - mh);                    \
      sh += (p0 + p1) + (p2 + p3);                                             \
      _Pragma("unroll") for (int r = 0; r < 4; r++)                            \
        acc[r] += p0 * f[0][r] + p1 * f[1][r] + p2 * f[2][r] + p3 * f[3][r];   \
    } else {                                                                   \
      float nm = fmaxf(mh, mc);                                                \
      float sc = __expf(mh - nm);                                              \
      float p0 = __expf(z[0] - nm), p1 = __expf(z[1] - nm);                    \
      float p2 = __expf(z[2] - nm), p3 = __expf(z[3] - nm);                    \
      sh = sh * sc + (p0 + p1) + (p2 + p3);                                    \
      mh = nm;                                                                 \
      _Pragma("unroll") for (int r = 0; r < 4; r++)                            \
        acc[r] = acc[r] * sc + p0 * f[0][r] + p1 * f[1][r] + p2 * f[2][r] +    \
                 p3 * f[3][r];                                                 \
    }                                                                          \
  }

template <int WRITE_BF16>
__global__ __launch_bounds__(128) void k_node5(const unsigned short* __restrict__ XLb,
                                               const float* __restrict__ XR,
                                               const int* __restrict__ rowptr,
                                               const int* __restrict__ deg,
                                               const int* __restrict__ ssrc,
                                               const int* __restrict__ order,
                                               const float* __restrict__ att,
                                               const float* __restrict__ bias,
                                               float* __restrict__ OUT,
                                               unsigned short* __restrict__ OAh) {
    int g = threadIdx.x >> 6;              // head-group: heads g*4 .. g*4+3
    int l = threadIdx.x & 63;
    int kb = blockIdx.x;
    int node = order[kb >> 1];             // degree-descending order
    int nid = ((kb & 1) << 13) | node;     // batch = kb&1 (NN = 2^13)
    int beg = rowptr[node], pend = rowptr[node + 1];
    int end = beg + deg[node];
    int hb = g * 256 + l * 4;              // 4 consecutive channels, one head

    const unsigned short* XLg = XLb + (size_t)(kb & 1) * NN * CH + hb;
    f32x4 xrv = *(const f32x4*)(XR + (size_t)nid * CH + hb);
    f32x4 atv = *(const f32x4*)(att + hb);
    f32x4 acc = {0.f, 0.f, 0.f, 0.f};
    float mh = -1e30f, sh = 0.f;

    i32x4 iA = *(const i32x4*)(ssrc + beg);
    i32x4 iB = iA;
    u16x4 curA[4], curB[4];
    GATHER(curA, iA);
    if (beg + 4 < pend) iB = *(const i32x4*)(ssrc + beg + 4);

    int base = beg;
    while (true) {
        // invariant: curA = data(c), iB = idx(c+1)
        if (base + 4 < pend) GATHER(curB, iB);
        if (base + 8 < pend) iA = *(const i32x4*)(ssrc + base + 8);
        PROCESS(curA, base);
        base += 4;
        if (base >= pend) break;
        // invariant: curB = data(c'), iA = idx(c'+1)
        if (base + 4 < pend) GATHER(curA, iA);
        if (base + 8 < pend) iB = *(const i32x4*)(ssrc + base + 8);
        PROCESS(curB, base);
        base += 4;
        if (base >= pend) break;
    }

    float inv = 1.f / sh;
    f32x4 biasv = *(const f32x4*)(bias + hb);
    size_t ob = (size_t)nid * CH + hb;
    if (WRITE_BF16) {
        u16x4 hv;
#pragma unroll
        for (int r = 0; r < 4; r++) {
            float wv = acc[r] * inv + biasv[r];
            hv[r] = bf16rne(wv);
        }
        *(u16x4*)(OAh + ob) = hv;
    } else {
        f32x4 ov;
#pragma unroll
        for (int r = 0; r < 4; r++) {
            float wv = acc[r] * inv + biasv[r];
            ov[r] = (wv > 0.f) ? wv : (__expf(wv) - 1.f);
        }
        *(f32x4*)(OUT + ob) = ov;
    }
}

// ---------- host ----------

extern "C" void kernel_launch(void* const* d_in, const int* in_sizes, int n_in,
                              void* d_out, int out_size, void* d_ws, size_t ws_size,
                              hipStream_t stream) {
    const float* x    = (const float*)d_in[0];
    const int*   ei   = (const int*)d_in[1];
    const float* W1l  = (const float*)d_in[2];
    const float* W1r  = (const float*)d_in[3];
    const float* att1 = (const float*)d_in[4];
    const float* b1   = (const float*)d_in[5];
    const float* W2l  = (const float*)d_in[6];
    const float* W2r  = (const float*)d_in[7];
    const float* att2 = (const float*)d_in[8];
    const float* b2   = (const float*)d_in[9];
    float* out = (float*)d_out;

    char* ws = (char*)d_ws;
    int* rowptr = (int*)ws;                 // NN+1
    int* cursor = rowptr + NN + 1;          // NN   (zeroed)
    int* deg    = cursor + NN;              // NN   (zeroed)
    int* hist   = deg + NN;                 // 256  (zeroed)
    int* order  = hist + 256;               // NN
    int* ssrc   = order + NN;               // SPAD (4-aligned padded)
    unsigned short* XLb = (unsigned short*)(((uintptr_t)(ssrc + SPAD) + 255) & ~(uintptr_t)255);
    float* XR = (float*)(XLb + (size_t)NT * CH);
    unsigned short* A_h = (unsigned short*)(XR + (size_t)NT * CH);  // NT*CH bf16
    unsigned short* W1h = A_h + (size_t)NT * CH;   // 1024*FIN
    unsigned short* W1o = W1h + 1024 * FIN;
    unsigned short* W2h = W1o + 1024 * FIN;        // 1024*CH
    unsigned short* W2o = W2h + 1024 * CH;

    hipMemsetAsync(cursor, 0, (size_t)(2 * NN + 256) * sizeof(int), stream);
    k_deg<<<(EPAD + 255) / 256, 256, 0, stream>>>(ei, deg);
    k_hist<<<NN / 256, 256, 0, stream>>>(deg, hist);
    k_binscan<<<1, 64, 0, stream>>>(hist);
    k_order<<<NN / 256, 256, 0, stream>>>(deg, hist, order);
    k_scan<<<1, 1024, 0, stream>>>(deg, rowptr);
    k_scatter<<<(EPAD + 255) / 256, 256, 0, stream>>>(ei, rowptr, cursor, ssrc);
    k_pad<<<NN / 256, 256, 0, stream>>>(rowptr, deg, ssrc);
    k_cvt_w<FIN><<<1024 * FIN / 256, 256, 0, stream>>>(W1l, W1r, W1h, W1o);
    k_cvt_w<CH><<<1024 * CH / 256, 256, 0, stream>>>(W2l, W2r, W2h, W2o);

    // layer 1 (both batches merged: NT rows) — B hi+lo for accuracy
    k_cvt_ah<<<NT * FIN / 4 / 256, 256, 0, stream>>>(x, A_h, NT * FIN / 4);
    k_gemm_mfma<FIN, 1><<<dim3(NT / 128, 8), 256, 0, stream>>>(A_h, W1h, W1o, XLb, XR);
    k_node5<1><<<NT, 128, 0, stream>>>(XLb, XR, rowptr, deg, ssrc, order, att1, b1, nullptr, A_h);
    // layer 2 — B hi only (error budget allows; 2/3 staging, half MFMA)
    k_gemm_mfma<CH, 0><<<dim3(NT / 128, 8), 256, 0, stream>>>(A_h, W2h, W2o, XLb, XR);
    k_node5<0><<<NT, 128, 0, stream>>>(XLb, XR, rowptr, deg, ssrc, order, att2, b2, out, nullptr);
}

// Round 17
// 221.946 us; speedup vs baseline: 1.1863x; 1.1863x over previous
//
#include <hip/hip_runtime.h>
#include <cstdint>

#define NN 8192
#define NT 16384         // 2 batches merged: total rows
#define EE 131072
#define EPAD (EE + NN)   // edges + self loops = 139264
#define SPAD (EPAD + 3 * NN)  // 4-aligned padded CSR capacity
#define FIN 128
#define CH 512           // H*HID = H*OUT
#define NH 8
#define NEG 0.2f

typedef __attribute__((ext_vector_type(8))) short short8;
typedef __attribute__((ext_vector_type(4))) unsigned short u16x4;
typedef __attribute__((ext_vector_type(4))) float f32x4;
typedef __attribute__((ext_vector_type(4))) int i32x4;

__device__ inline unsigned short bf16rne(float x) {
    unsigned u = __float_as_uint(x);
    unsigned r = (u + 0x7FFFu + ((u >> 16) & 1u)) >> 16;
    return (unsigned short)r;
}
__device__ inline float bf16tof(unsigned short h) {
    return __uint_as_float((unsigned)h << 16);
}
__device__ inline void gload16(const void* g, void* l) {
    __builtin_amdgcn_global_load_lds((const __attribute__((address_space(1))) void*)g,
                                     (__attribute__((address_space(3))) void*)l, 16, 0, 0);
}
// cross-lane add via DPP (VALU only, no DS crossbar). CTRL: 0xB1=quad_perm
// xor1, 0x4E=quad_perm xor2, 0x124=row_ror:4, 0x128=row_ror:8.
template <int CTRL>
__device__ inline float dpp_add(float x) {
    int v = __builtin_amdgcn_update_dpp(0, __float_as_int(x), CTRL, 0xF, 0xF, true);
    return x + __int_as_float(v);
}

// ---------- CSR build (4-aligned padded segments) ----------

__global__ __launch_bounds__(256) void k_deg(const int* __restrict__ ei, int* __restrict__ deg) {
    int e = blockIdx.x * 256 + threadIdx.x;
    if (e >= EPAD) return;
    int dst = (e < EE) ? ei[EE + e] : (e - EE);
    atomicAdd(&deg[dst], 1);
}

__global__ __launch_bounds__(1024) void k_scan(const int* __restrict__ deg, int* __restrict__ rowptr) {
    __shared__ int part[1024];
    int t = threadIdx.x;
    int loc[8];
    int s = 0;
#pragma unroll
    for (int i = 0; i < 8; i++) { loc[i] = s; s += (deg[t * 8 + i] + 3) & ~3; }
    part[t] = s;
    __syncthreads();
    if (t == 0) {
        int run = 0;
        for (int i = 0; i < 1024; i++) { int tmp = part[i]; part[i] = run; run += tmp; }
        rowptr[NN] = run;
    }
    __syncthreads();
    int base = part[t];
#pragma unroll
    for (int i = 0; i < 8; i++) rowptr[t * 8 + i] = base + loc[i];
}

__global__ __launch_bounds__(256) void k_scatter(const int* __restrict__ ei, const int* __restrict__ rowptr,
                                                 int* __restrict__ cursor, int* __restrict__ ssrc) {
    int e = blockIdx.x * 256 + threadIdx.x;
    if (e >= EPAD) return;
    int src = (e < EE) ? ei[e] : (e - EE);
    int dst = (e < EE) ? ei[EE + e] : (e - EE);
    int pos = rowptr[dst] + atomicAdd(&cursor[dst], 1);
    ssrc[pos] = src;
}

// fill pad slots with src=0 (row 0 gather, masked out of softmax)
__global__ __launch_bounds__(256) void k_pad(const int* __restrict__ rowptr, const int* __restrict__ deg,
                                             int* __restrict__ ssrc) {
    int n = blockIdx.x * 256 + threadIdx.x;
    if (n >= NN) return;
    int e = rowptr[n] + deg[n], pe = rowptr[n + 1];
    for (int i = e; i < pe; i++) ssrc[i] = 0;
}

// ---------- conversions ----------

__global__ __launch_bounds__(256) void k_cvt_ah(const float* __restrict__ F,
                                                unsigned short* __restrict__ Ah, int n4) {
    int i = blockIdx.x * 256 + threadIdx.x;
    if (i >= n4) return;
    f32x4 v = ((const f32x4*)F)[i];
#pragma unroll
    for (int c = 0; c < 4; c++) Ah[i * 4 + c] = bf16rne(v[c]);
}

// W[K][512] (Wl,Wr) -> Wt[n=1024][K] hi/lo (transposed, K contiguous)
template <int K>
__global__ __launch_bounds__(256) void k_cvt_w(const float* __restrict__ Wl, const float* __restrict__ Wr,
                                               unsigned short* __restrict__ Wh, unsigned short* __restrict__ Wlo) {
    int idx = blockIdx.x * 256 + threadIdx.x;   // = n*K + k
    int n = idx / K, k = idx % K;
    const float* W = (n < 512) ? Wl : Wr;
    float x = W[k * 512 + (n & 511)];
    unsigned short h = bf16rne(x);
    Wh[idx] = h;
    Wlo[idx] = bf16rne(x - bf16tof(h));
}

// ---------- split-bf16 MFMA GEMM: [NT x K] @ [K x 1024] -> XLb (bf16) | XR (f32) ----------
// A in bf16-hi. USE_BL=1: B in hi+lo (2 MFMA/frag). USE_BL=0: B hi only
// (layer 2; error budget allows). BK = K-slab per barrier phase: BK=64
// halves the vmcnt(0)+barrier drains vs BK=32 (amortizes the 2-barrier
// structural stall; LDS 32KB still allows 5 blocks/CU at VGPR 100).

template <int K, int USE_BL, int BK>
__global__ __launch_bounds__(256) void k_gemm_mfma(const unsigned short* __restrict__ Ah,
                                                   const unsigned short* __restrict__ Bh,
                                                   const unsigned short* __restrict__ Bl,
                                                   unsigned short* __restrict__ XLb,
                                                   float* __restrict__ XR) {
    const int NS = BK / 8;               // kh slices per slab
    __shared__ unsigned short sAh[NS][128][8], sBh[NS][128][8];
    __shared__ unsigned short sBl[USE_BL ? NS : 1][128][8];
    int tid = threadIdx.x;
    int l = tid & 63;
    int w = tid >> 6, wm = w >> 1, wn = w & 1;
    int m0 = blockIdx.x * 128, n0 = blockIdx.y * 128;
    int lr = l & 15, kh = l >> 4;
    f32x4 acc[4][4] = {};

    for (int k0 = 0; k0 < K; k0 += BK) {
#pragma unroll
        for (int g = 0; g < NS / 2; g++) {
            int cell = g * 256 + tid;
            int ckh = cell >> 7, cr = cell & 127;
            int ka = k0 + ckh * 8;
            gload16(Ah + (size_t)(m0 + cr) * K + ka, &sAh[ckh][cr][0]);
            gload16(Bh + (size_t)(n0 + cr) * K + ka, &sBh[ckh][cr][0]);
            if (USE_BL) gload16(Bl + (size_t)(n0 + cr) * K + ka, &sBl[ckh][cr][0]);
        }
        __syncthreads();
#pragma unroll
        for (int kk = 0; kk < BK / 32; kk++) {
            int ks = kk * 4 + kh;
            short8 fah[4], fbh[4], fbl[4];
#pragma unroll
            for (int i = 0; i < 4; i++) {
                fah[i] = *(const short8*)&sAh[ks][wm * 64 + i * 16 + lr][0];
                fbh[i] = *(const short8*)&sBh[ks][wn * 64 + i * 16 + lr][0];
                if (USE_BL) fbl[i] = *(const short8*)&sBl[ks][wn * 64 + i * 16 + lr][0];
            }
#pragma unroll
            for (int i = 0; i < 4; i++)
#pragma unroll
                for (int j = 0; j < 4; j++) {
                    if (USE_BL)
                        acc[i][j] = __builtin_amdgcn_mfma_f32_16x16x32_bf16(fah[i], fbl[j], acc[i][j], 0, 0, 0);
                    acc[i][j] = __builtin_amdgcn_mfma_f32_16x16x32_bf16(fah[i], fbh[j], acc[i][j], 0, 0, 0);
                }
        }
        __syncthreads();
    }
    // C/D layout: col = lane&15, row = (lane>>4)*4 + q  [m89-verified]
    int colt = n0 + wn * 64;     // wave-uniform
    int cb = colt & 511;
    if (colt < 512) {
#pragma unroll
        for (int i = 0; i < 4; i++) {
            int mg = m0 + wm * 64 + i * 16 + kh * 4;
#pragma unroll
            for (int j = 0; j < 4; j++) {
                int cg = cb + j * 16 + lr;
#pragma unroll
                for (int q = 0; q < 4; q++)
                    XLb[(size_t)(mg + q) * CH + cg] = bf16rne(acc[i][j][q]);
            }
        }
    } else {
#pragma unroll
        for (int i = 0; i < 4; i++) {
            int mg = m0 + wm * 64 + i * 16 + kh * 4;
#pragma unroll
            for (int j = 0; j < 4; j++) {
                int cg = cb + j * 16 + lr;
#pragma unroll
                for (int q = 0; q < 4; q++)
                    XR[(size_t)(mg + q) * CH + cg] = acc[i][j][q];
            }
        }
    }
}

// ---------- fused per-node: logits + online softmax + aggregation ----------
// r15 structure (verbatim): both batches in one launch; 2 consecutive nids
// per 256-thread block; 2 waves per node (head-group g); lane l owns 4
// consecutive channels g*256+l*4 (one head). 3-deep pipeline over 4-edge
// chunks (idx int4 + gathers in flight). Single bf16->f32 convert per value;
// lrelu = max(t, 0.2t). DPP-only fold; per-lane softmax state; defer-rescale
// THR=8. Tail/pad edges masked via z=-1e30 (pads gather row 0, valid).

#define GATHER(CX, IV)                                                         \
  {                                                                            \
    CX[0] = *(const u16x4*)(XLg + (size_t)IV[0] * CH);                         \
    CX[1] = *(const u16x4*)(XLg + (size_t)IV[1] * CH);                         \
    CX[2] = *(const u16x4*)(XLg + (size_t)IV[2] * CH);                         \
    CX[3] = *(const u16x4*)(XLg + (size_t)IV[3] * CH);                         \
  }

#define PROCESS(CX, cb)                                                        \
  {                                                                            \
    float f[4][4];                                                             \
    _Pragma("unroll") for (int e = 0; e < 4; e++)                              \
      _Pragma("unroll") for (int r = 0; r < 4; r++)                            \
        f[e][r] = bf16tof(CX[e][r]);                                           \
    float z[4];                                                                \
    _Pragma("unroll") for (int e = 0; e < 4; e++) {                            \
      float s = 0.f;                                                           \
      _Pragma("unroll") for (int r = 0; r < 4; r++) {                          \
        float t = f[e][r] + xrv[r];                                            \
        t = fmaxf(t, NEG * t);                                                 \
        s += t * atv[r];                                                       \
      }                                                                        \
      z[e] = s;                                                                \
    }                                                                          \
    _Pragma("unroll") for (int e = 0; e < 4; e++) {                            \
      z[e] = dpp_add<0xB1>(z[e]);                                              \
      z[e] = dpp_add<0x4E>(z[e]);                                              \
      z[e] = dpp_add<0x124>(z[e]);                                             \
      z[e] = dpp_add<0x128>(z[e]);                                             \
    }                                                                          \
    _Pragma("unroll") for (int e = 1; e < 4; e++)                              \
      if ((cb) + e >= end) z[e] = -1e30f;                                      \
    float mc = fmaxf(fmaxf(z[0], z[1]), fmaxf(z[2], z[3]));                    \
    if (__ballot(mc > mh + 8.f) == 0ULL) {                                     \
      float p0 = __expf(z[0] - mh), p1 = __expf(z[1] - mh);                    \
      float p2 = __expf(z[2] - mh), p3 = __expf(z[3] - mh);                    \
      sh += (p0 + p1) + (p2 + p3);                                             \
      _Pragma("unroll") for (int r = 0; r < 4; r++)                            \
        acc[r] += p0 * f[0][r] + p1 * f[1][r] + p2 * f[2][r] + p3 * f[3][r];   \
    } else {                                                                   \
      float nm = fmaxf(mh, mc);                                                \
      float sc = __expf(mh - nm);                                              \
      float p0 = __expf(z[0] - nm), p1 = __expf(z[1] - nm);                    \
      float p2 = __expf(z[2] - nm), p3 = __expf(z[3] - nm);                    \
      sh = sh * sc + (p0 + p1) + (p2 + p3);                                    \
      mh = nm;                                                                 \
      _Pragma("unroll") for (int r = 0; r < 4; r++)                            \
        acc[r] = acc[r] * sc + p0 * f[0][r] + p1 * f[1][r] + p2 * f[2][r] +    \
                 p3 * f[3][r];                                                 \
    }                                                                          \
  }

template <int WRITE_BF16>
__global__ __launch_bounds__(256) void k_node5(const unsigned short* __restrict__ XLb,
                                               const float* __restrict__ XR,
                                               const int* __restrict__ rowptr,
                                               const int* __restrict__ deg,
                                               const int* __restrict__ ssrc,
                                               const float* __restrict__ att,
                                               const float* __restrict__ bias,
                                               float* __restrict__ OUT,
                                               unsigned short* __restrict__ OAh) {
    int w = threadIdx.x >> 6;
    int nid = blockIdx.x * 2 + (w >> 1);   // global row 0..NT-1
    int g = w & 1;                         // head-group: heads g*4 .. g*4+3
    int l = threadIdx.x & 63;
    int node = nid & (NN - 1);
    int beg = rowptr[node], pend = rowptr[node + 1];
    int end = beg + deg[node];
    int hb = g * 256 + l * 4;              // 4 consecutive channels, one head

    const unsigned short* XLg = XLb + (size_t)(nid >> 13) * NN * CH + hb;
    f32x4 xrv = *(const f32x4*)(XR + (size_t)nid * CH + hb);
    f32x4 atv = *(const f32x4*)(att + hb);
    f32x4 acc = {0.f, 0.f, 0.f, 0.f};
    float mh = -1e30f, sh = 0.f;

    i32x4 iA = *(const i32x4*)(ssrc + beg);
    i32x4 iB = iA;
    u16x4 curA[4], curB[4];
    GATHER(curA, iA);
    if (beg + 4 < pend) iB = *(const i32x4*)(ssrc + beg + 4);

    int base = beg;
    while (true) {
        // invariant: curA = data(c), iB = idx(c+1)
        if (base + 4 < pend) GATHER(curB, iB);
        if (base + 8 < pend) iA = *(const i32x4*)(ssrc + base + 8);
        PROCESS(curA, base);
        base += 4;
        if (base >= pend) break;
        // invariant: curB = data(c'), iA = idx(c'+1)
        if (base + 4 < pend) GATHER(curA, iA);
        if (base + 8 < pend) iB = *(const i32x4*)(ssrc + base + 8);
        PROCESS(curB, base);
        base += 4;
        if (base >= pend) break;
    }

    float inv = 1.f / sh;
    f32x4 biasv = *(const f32x4*)(bias + hb);
    size_t ob = (size_t)nid * CH + hb;
    if (WRITE_BF16) {
        u16x4 hv;
#pragma unroll
        for (int r = 0; r < 4; r++) {
            float wv = acc[r] * inv + biasv[r];
            hv[r] = bf16rne(wv);
        }
        *(u16x4*)(OAh + ob) = hv;
    } else {
        f32x4 ov;
#pragma unroll
        for (int r = 0; r < 4; r++) {
            float wv = acc[r] * inv + biasv[r];
            ov[r] = (wv > 0.f) ? wv : (__expf(wv) - 1.f);
        }
        *(f32x4*)(OUT + ob) = ov;
    }
}

// ---------- host ----------

extern "C" void kernel_launch(void* const* d_in, const int* in_sizes, int n_in,
                              void* d_out, int out_size, void* d_ws, size_t ws_size,
                              hipStream_t stream) {
    const float* x    = (const float*)d_in[0];
    const int*   ei   = (const int*)d_in[1];
    const float* W1l  = (const float*)d_in[2];
    const float* W1r  = (const float*)d_in[3];
    const float* att1 = (const float*)d_in[4];
    const float* b1   = (const float*)d_in[5];
    const float* W2l  = (const float*)d_in[6];
    const float* W2r  = (const float*)d_in[7];
    const float* att2 = (const float*)d_in[8];
    const float* b2   = (const float*)d_in[9];
    float* out = (float*)d_out;

    char* ws = (char*)d_ws;
    int* rowptr = (int*)ws;                 // NN+1
    int* cursor = rowptr + NN + 1;          // NN   (zeroed)
    int* deg    = cursor + NN;              // NN   (zeroed)
    int* ssrc   = deg + NN;                 // SPAD (4-aligned padded)
    unsigned short* XLb = (unsigned short*)(((uintptr_t)(ssrc + SPAD) + 255) & ~(uintptr_t)255);
    float* XR = (float*)(XLb + (size_t)NT * CH);
    unsigned short* A_h = (unsigned short*)(XR + (size_t)NT * CH);  // NT*CH bf16
    unsigned short* W1h = A_h + (size_t)NT * CH;   // 1024*FIN
    unsigned short* W1o = W1h + 1024 * FIN;
    unsigned short* W2h = W1o + 1024 * FIN;        // 1024*CH
    unsigned short* W2o = W2h + 1024 * CH;

    hipMemsetAsync(cursor, 0, (size_t)2 * NN * sizeof(int), stream);
    k_deg<<<(EPAD + 255) / 256, 256, 0, stream>>>(ei, deg);
    k_scan<<<1, 1024, 0, stream>>>(deg, rowptr);
    k_scatter<<<(EPAD + 255) / 256, 256, 0, stream>>>(ei, rowptr, cursor, ssrc);
    k_pad<<<NN / 256, 256, 0, stream>>>(rowptr, deg, ssrc);
    k_cvt_w<FIN><<<1024 * FIN / 256, 256, 0, stream>>>(W1l, W1r, W1h, W1o);
    k_cvt_w<CH><<<1024 * CH / 256, 256, 0, stream>>>(W2l, W2r, W2h, W2o);

    // layer 1 (both batches merged: NT rows) — B hi+lo for accuracy, BK=32
    k_cvt_ah<<<NT * FIN / 4 / 256, 256, 0, stream>>>(x, A_h, NT * FIN / 4);
    k_gemm_mfma<FIN, 1, 32><<<dim3(NT / 128, 8), 256, 0, stream>>>(A_h, W1h, W1o, XLb, XR);
    k_node5<1><<<NT / 2, 256, 0, stream>>>(XLb, XR, rowptr, deg, ssrc, att1, b1, nullptr, A_h);
    // layer 2 — B hi only, BK=64 (half the barrier drains)
    k_gemm_mfma<CH, 0, 64><<<dim3(NT / 128, 8), 256, 0, stream>>>(A_h, W2h, W2o, XLb, XR);
    k_node5<0><<<NT / 2, 256, 0, stream>>>(XLb, XR, rowptr, deg, ssrc, att2, b2, out, nullptr);
}

// Round 18
// 210.892 us; speedup vs baseline: 1.2484x; 1.0524x over previous
//
#include <hip/hip_runtime.h>
#include <cstdint>

#define NN 8192
#define NT 16384         // 2 batches merged: total rows
#define EE 131072
#define EPAD (EE + NN)   // edges + self loops = 139264
#define SPAD (EPAD + 3 * NN)  // 4-aligned padded CSR capacity
#define FIN 128
#define CH 512           // H*HID = H*OUT
#define NH 8
#define NEG 0.2f

typedef __attribute__((ext_vector_type(8))) short short8;
typedef __attribute__((ext_vector_type(4))) unsigned short u16x4;
typedef __attribute__((ext_vector_type(4))) float f32x4;
typedef __attribute__((ext_vector_type(4))) int i32x4;

__device__ inline unsigned short bf16rne(float x) {
    unsigned u = __float_as_uint(x);
    unsigned r = (u + 0x7FFFu + ((u >> 16) & 1u)) >> 16;
    return (unsigned short)r;
}
__device__ inline float bf16tof(unsigned short h) {
    return __uint_as_float((unsigned)h << 16);
}
__device__ inline void gload16(const void* g, void* l) {
    __builtin_amdgcn_global_load_lds((const __attribute__((address_space(1))) void*)g,
                                     (__attribute__((address_space(3))) void*)l, 16, 0, 0);
}
// cross-lane add via DPP (VALU only, no DS crossbar). CTRL: 0xB1=quad_perm
// xor1, 0x4E=quad_perm xor2, 0x124=row_ror:4, 0x128=row_ror:8.
template <int CTRL>
__device__ inline float dpp_add(float x) {
    int v = __builtin_amdgcn_update_dpp(0, __float_as_int(x), CTRL, 0xF, 0xF, true);
    return x + __int_as_float(v);
}

// ---------- CSR build (4-aligned padded segments) ----------

__global__ __launch_bounds__(256) void k_deg(const int* __restrict__ ei, int* __restrict__ deg) {
    int e = blockIdx.x * 256 + threadIdx.x;
    if (e >= EPAD) return;
    int dst = (e < EE) ? ei[EE + e] : (e - EE);
    atomicAdd(&deg[dst], 1);
}

// log-depth scan (wave shfl_up + wave-total scan) — replaces the serial
// t==0 loop (≈1024-long LDS dependency chain) of the old version.
__global__ __launch_bounds__(1024) void k_scan(const int* __restrict__ deg, int* __restrict__ rowptr) {
    __shared__ int wsum[16];
    int t = threadIdx.x;
    int lane = t & 63, wid = t >> 6;
    int loc[8];
    int s = 0;
#pragma unroll
    for (int i = 0; i < 8; i++) { loc[i] = s; s += (deg[t * 8 + i] + 3) & ~3; }
    int inc = s;
#pragma unroll
    for (int off = 1; off < 64; off <<= 1) {
        int v = __shfl_up(inc, off);
        if (lane >= off) inc += v;
    }
    if (lane == 63) wsum[wid] = inc;
    __syncthreads();
    if (wid == 0 && lane < 16) {
        int v = wsum[lane];
#pragma unroll
        for (int off = 1; off < 16; off <<= 1) {
            int u = __shfl_up(v, off);
            if (lane >= off) v += u;
        }
        wsum[lane] = v;
    }
    __syncthreads();
    int wbase = (wid == 0) ? 0 : wsum[wid - 1];
    int base = wbase + inc - s;          // exclusive prefix for this thread
#pragma unroll
    for (int i = 0; i < 8; i++) rowptr[t * 8 + i] = base + loc[i];
    if (t == 1023) rowptr[NN] = wbase + inc;
}

__global__ __launch_bounds__(256) void k_scatter(const int* __restrict__ ei, const int* __restrict__ rowptr,
                                                 int* __restrict__ cursor, int* __restrict__ ssrc) {
    int e = blockIdx.x * 256 + threadIdx.x;
    if (e >= EPAD) return;
    int src = (e < EE) ? ei[e] : (e - EE);
    int dst = (e < EE) ? ei[EE + e] : (e - EE);
    int pos = rowptr[dst] + atomicAdd(&cursor[dst], 1);
    ssrc[pos] = src;
}

// fill pad slots with src=0 (row 0 gather, masked out of softmax)
__global__ __launch_bounds__(256) void k_pad(const int* __restrict__ rowptr, const int* __restrict__ deg,
                                             int* __restrict__ ssrc) {
    int n = blockIdx.x * 256 + threadIdx.x;
    if (n >= NN) return;
    int e = rowptr[n] + deg[n], pe = rowptr[n + 1];
    for (int i = e; i < pe; i++) ssrc[i] = 0;
}

// ---------- conversions ----------

__global__ __launch_bounds__(256) void k_cvt_ah(const float* __restrict__ F,
                                                unsigned short* __restrict__ Ah, int n4) {
    int i = blockIdx.x * 256 + threadIdx.x;
    if (i >= n4) return;
    f32x4 v = ((const f32x4*)F)[i];
#pragma unroll
    for (int c = 0; c < 4; c++) Ah[i * 4 + c] = bf16rne(v[c]);
}

// W[K][512] (Wl,Wr) -> Wt[n=1024][K] bf16-hi (transposed, K contiguous)
template <int K>
__global__ __launch_bounds__(256) void k_cvt_w(const float* __restrict__ Wl, const float* __restrict__ Wr,
                                               unsigned short* __restrict__ Wh) {
    int idx = blockIdx.x * 256 + threadIdx.x;   // = n*K + k
    int n = idx / K, k = idx % K;
    const float* W = (n < 512) ? Wl : Wr;
    Wh[idx] = bf16rne(W[k * 512 + (n & 511)]);
}

// ---------- bf16 MFMA GEMM: [NT x K] @ [K x 1024] -> XLb (bf16) | XR (f32) ----------
// A and B both bf16-hi. B-lo dropped for BOTH layers: layer-1's XL output is
// rounded to bf16 anyway (2^-8 floor), so B-lo polish is below the noise;
// layer-2 verified in r15 (absmax unchanged). BK=64: one barrier pair per
// 64-K slab. Single-buffer m97 loop (dbuf regressed, r13).

template <int K, int BK>
__global__ __launch_bounds__(256) void k_gemm_mfma(const unsigned short* __restrict__ Ah,
                                                   const unsigned short* __restrict__ Bh,
                                                   unsigned short* __restrict__ XLb,
                                                   float* __restrict__ XR) {
    const int NS = BK / 8;               // kh slices per slab
    __shared__ unsigned short sAh[NS][128][8], sBh[NS][128][8];
    int tid = threadIdx.x;
    int l = tid & 63;
    int w = tid >> 6, wm = w >> 1, wn = w & 1;
    int m0 = blockIdx.x * 128, n0 = blockIdx.y * 128;
    int lr = l & 15, kh = l >> 4;
    f32x4 acc[4][4] = {};

    for (int k0 = 0; k0 < K; k0 += BK) {
#pragma unroll
        for (int g = 0; g < NS / 2; g++) {
            int cell = g * 256 + tid;
            int ckh = cell >> 7, cr = cell & 127;
            int ka = k0 + ckh * 8;
            gload16(Ah + (size_t)(m0 + cr) * K + ka, &sAh[ckh][cr][0]);
            gload16(Bh + (size_t)(n0 + cr) * K + ka, &sBh[ckh][cr][0]);
        }
        __syncthreads();
#pragma unroll
        for (int kk = 0; kk < BK / 32; kk++) {
            int ks = kk * 4 + kh;
            short8 fah[4], fbh[4];
#pragma unroll
            for (int i = 0; i < 4; i++) {
                fah[i] = *(const short8*)&sAh[ks][wm * 64 + i * 16 + lr][0];
                fbh[i] = *(const short8*)&sBh[ks][wn * 64 + i * 16 + lr][0];
            }
#pragma unroll
            for (int i = 0; i < 4; i++)
#pragma unroll
                for (int j = 0; j < 4; j++)
                    acc[i][j] = __builtin_amdgcn_mfma_f32_16x16x32_bf16(fah[i], fbh[j], acc[i][j], 0, 0, 0);
        }
        __syncthreads();
    }
    // C/D layout: col = lane&15, row = (lane>>4)*4 + q  [m89-verified]
    int colt = n0 + wn * 64;     // wave-uniform
    int cb = colt & 511;
    if (colt < 512) {
#pragma unroll
        for (int i = 0; i < 4; i++) {
            int mg = m0 + wm * 64 + i * 16 + kh * 4;
#pragma unroll
            for (int j = 0; j < 4; j++) {
                int cg = cb + j * 16 + lr;
#pragma unroll
                for (int q = 0; q < 4; q++)
                    XLb[(size_t)(mg + q) * CH + cg] = bf16rne(acc[i][j][q]);
            }
        }
    } else {
#pragma unroll
        for (int i = 0; i < 4; i++) {
            int mg = m0 + wm * 64 + i * 16 + kh * 4;
#pragma unroll
            for (int j = 0; j < 4; j++) {
                int cg = cb + j * 16 + lr;
#pragma unroll
                for (int q = 0; q < 4; q++)
                    XR[(size_t)(mg + q) * CH + cg] = acc[i][j][q];
            }
        }
    }
}

// ---------- fused per-node: logits + online softmax + aggregation ----------
// r15 structure: both batches in one launch; 2 consecutive nids per
// 256-thread block; 2 waves per node (head-group g); lane l owns 4
// consecutive channels g*256+l*4 (one head). 3-deep pipeline over 4-edge
// chunks (idx int4 + gathers in flight). Single bf16->f32 convert per value;
// lrelu = max(t, 0.2t). DPP-only fold; per-lane softmax state; defer-rescale
// THR=8. Tail/pad edges masked via z=-1e30 (pads gather row 0, valid).

#define GATHER(CX, IV)                                                         \
  {                                                                            \
    CX[0] = *(const u16x4*)(XLg + (size_t)IV[0] * CH);                         \
    CX[1] = *(const u16x4*)(XLg + (size_t)IV[1] * CH);                         \
    CX[2] = *(const u16x4*)(XLg + (size_t)IV[2] * CH);                         \
    CX[3] = *(const u16x4*)(XLg + (size_t)IV[3] * CH);                         \
  }

#define PROCESS(CX, cb)                                                        \
  {                                                                            \
    float f[4][4];                                                             \
    _Pragma("unroll") for (int e = 0; e < 4; e++)                              \
      _Pragma("unroll") for (int r = 0; r < 4; r++)                            \
        f[e][r] = bf16tof(CX[e][r]);                                           \
    float z[4];                                                                \
    _Pragma("unroll") for (int e = 0; e < 4; e++) {                            \
      float s = 0.f;                                                           \
      _Pragma("unroll") for (int r = 0; r < 4; r++) {                          \
        float t = f[e][r] + xrv[r];                                            \
        t = fmaxf(t, NEG * t);                                                 \
        s += t * atv[r];                                                       \
      }                                                                        \
      z[e] = s;                                                                \
    }                                                                          \
    _Pragma("unroll") for (int e = 0; e < 4; e++) {                            \
      z[e] = dpp_add<0xB1>(z[e]);                                              \
      z[e] = dpp_add<0x4E>(z[e]);                                              \
      z[e] = dpp_add<0x124>(z[e]);                                             \
      z[e] = dpp_add<0x128>(z[e]);                                             \
    }                                                                          \
    _Pragma("unroll") for (int e = 1; e < 4; e++)                              \
      if ((cb) + e >= end) z[e] = -1e30f;                                      \
    float mc = fmaxf(fmaxf(z[0], z[1]), fmaxf(z[2], z[3]));                    \
    if (__ballot(mc > mh + 8.f) == 0ULL) {                                     \
      float p0 = __expf(z[0] - mh), p1 = __expf(z[1] - mh);                    \
      float p2 = __expf(z[2] - mh), p3 = __expf(z[3] - mh);                    \
      sh += (p0 + p1) + (p2 + p3);                                             \
      _Pragma("unroll") for (int r = 0; r < 4; r++)                            \
        acc[r] += p0 * f[0][r] + p1 * f[1][r] + p2 * f[2][r] + p3 * f[3][r];   \
    } else {                                                                   \
      float nm = fmaxf(mh, mc);                                                \
      float sc = __expf(mh - nm);                                              \
      float p0 = __expf(z[0] - nm), p1 = __expf(z[1] - nm);                    \
      float p2 = __expf(z[2] - nm), p3 = __expf(z[3] - nm);                    \
      sh = sh * sc + (p0 + p1) + (p2 + p3);                                    \
      mh = nm;                                                                 \
      _Pragma("unroll") for (int r = 0; r < 4; r++)                            \
        acc[r] = acc[r] * sc + p0 * f[0][r] + p1 * f[1][r] + p2 * f[2][r] +    \
                 p3 * f[3][r];                                                 \
    }                                                                          \
  }

template <int WRITE_BF16>
__global__ __launch_bounds__(256) void k_node5(const unsigned short* __restrict__ XLb,
                                               const float* __restrict__ XR,
                                               const int* __restrict__ rowptr,
                                               const int* __restrict__ deg,
                                               const int* __restrict__ ssrc,
                                               const float* __restrict__ att,
                                               const float* __restrict__ bias,
                                               float* __restrict__ OUT,
                                               unsigned short* __restrict__ OAh) {
    int w = threadIdx.x >> 6;
    int nid = blockIdx.x * 2 + (w >> 1);   // global row 0..NT-1
    int g = w & 1;                         // head-group: heads g*4 .. g*4+3
    int l = threadIdx.x & 63;
    int node = nid & (NN - 1);
    int beg = rowptr[node], pend = rowptr[node + 1];
    int end = beg + deg[node];
    int hb = g * 256 + l * 4;              // 4 consecutive channels, one head

    const unsigned short* XLg = XLb + (size_t)(nid >> 13) * NN * CH + hb;
    f32x4 xrv = *(const f32x4*)(XR + (size_t)nid * CH + hb);
    f32x4 atv = *(const f32x4*)(att + hb);
    f32x4 acc = {0.f, 0.f, 0.f, 0.f};
    float mh = -1e30f, sh = 0.f;

    i32x4 iA = *(const i32x4*)(ssrc + beg);
    i32x4 iB = iA;
    u16x4 curA[4], curB[4];
    GATHER(curA, iA);
    if (beg + 4 < pend) iB = *(const i32x4*)(ssrc + beg + 4);

    int base = beg;
    while (true) {
        // invariant: curA = data(c), iB = idx(c+1)
        if (base + 4 < pend) GATHER(curB, iB);
        if (base + 8 < pend) iA = *(const i32x4*)(ssrc + base + 8);
        PROCESS(curA, base);
        base += 4;
        if (base >= pend) break;
        // invariant: curB = data(c'), iA = idx(c'+1)
        if (base + 4 < pend) GATHER(curA, iA);
        if (base + 8 < pend) iB = *(const i32x4*)(ssrc + base + 8);
        PROCESS(curB, base);
        base += 4;
        if (base >= pend) break;
    }

    float inv = 1.f / sh;
    f32x4 biasv = *(const f32x4*)(bias + hb);
    size_t ob = (size_t)nid * CH + hb;
    if (WRITE_BF16) {
        u16x4 hv;
#pragma unroll
        for (int r = 0; r < 4; r++) {
            float wv = acc[r] * inv + biasv[r];
            hv[r] = bf16rne(wv);
        }
        *(u16x4*)(OAh + ob) = hv;
    } else {
        f32x4 ov;
#pragma unroll
        for (int r = 0; r < 4; r++) {
            float wv = acc[r] * inv + biasv[r];
            ov[r] = (wv > 0.f) ? wv : (__expf(wv) - 1.f);
        }
        *(f32x4*)(OUT + ob) = ov;
    }
}

// ---------- host ----------

extern "C" void kernel_launch(void* const* d_in, const int* in_sizes, int n_in,
                              void* d_out, int out_size, void* d_ws, size_t ws_size,
                              hipStream_t stream) {
    const float* x    = (const float*)d_in[0];
    const int*   ei   = (const int*)d_in[1];
    const float* W1l  = (const float*)d_in[2];
    const float* W1r  = (const float*)d_in[3];
    const float* att1 = (const float*)d_in[4];
    const float* b1   = (const float*)d_in[5];
    const float* W2l  = (const float*)d_in[6];
    const float* W2r  = (const float*)d_in[7];
    const float* att2 = (const float*)d_in[8];
    const float* b2   = (const float*)d_in[9];
    float* out = (float*)d_out;

    char* ws = (char*)d_ws;
    int* rowptr = (int*)ws;                 // NN+1
    int* cursor = rowptr + NN + 1;          // NN   (zeroed)
    int* deg    = cursor + NN;              // NN   (zeroed)
    int* ssrc   = deg + NN;                 // SPAD (4-aligned padded)
    unsigned short* XLb = (unsigned short*)(((uintptr_t)(ssrc + SPAD) + 255) & ~(uintptr_t)255);
    float* XR = (float*)(XLb + (size_t)NT * CH);
    unsigned short* A_h = (unsigned short*)(XR + (size_t)NT * CH);  // NT*CH bf16
    unsigned short* W1h = A_h + (size_t)NT * CH;   // 1024*FIN
    unsigned short* W2h = W1h + 1024 * FIN;        // 1024*CH
    unsigned short* W2o = W2h + 1024 * CH;         // (unused spare)

    (void)W2o;
    hipMemsetAsync(cursor, 0, (size_t)2 * NN * sizeof(int), stream);
    k_deg<<<(EPAD + 255) / 256, 256, 0, stream>>>(ei, deg);
    k_scan<<<1, 1024, 0, stream>>>(deg, rowptr);
    k_scatter<<<(EPAD + 255) / 256, 256, 0, stream>>>(ei, rowptr, cursor, ssrc);
    k_pad<<<NN / 256, 256, 0, stream>>>(rowptr, deg, ssrc);
    k_cvt_w<FIN><<<1024 * FIN / 256, 256, 0, stream>>>(W1l, W1r, W1h);
    k_cvt_w<CH><<<1024 * CH / 256, 256, 0, stream>>>(W2l, W2r, W2h);

    // layer 1 (both batches merged: NT rows)
    k_cvt_ah<<<NT * FIN / 4 / 256, 256, 0, stream>>>(x, A_h, NT * FIN / 4);
    k_gemm_mfma<FIN, 64><<<dim3(NT / 128, 8), 256, 0, stream>>>(A_h, W1h, XLb, XR);
    k_node5<1><<<NT / 2, 256, 0, stream>>>(XLb, XR, rowptr, deg, ssrc, att1, b1, nullptr, A_h);
    // layer 2
    k_gemm_mfma<CH, 64><<<dim3(NT / 128, 8), 256, 0, stream>>>(A_h, W2h, XLb, XR);
    k_node5<0><<<NT / 2, 256, 0, stream>>>(XLb, XR, rowptr, deg, ssrc, att2, b2, out, nullptr);
}

// Round 19
// 210.889 us; speedup vs baseline: 1.2485x; 1.0000x over previous
//
#include <hip/hip_runtime.h>
#include <cstdint>

#define NN 8192
#define NT 16384         // 2 batches merged: total rows
#define EE 131072
#define EPAD (EE + NN)   // edges + self loops = 139264
#define SPAD (EPAD + 3 * NN)  // 4-aligned padded CSR capacity
#define FIN 128
#define CH 512           // H*HID = H*OUT
#define NH 8
#define NEG 0.2f

typedef __attribute__((ext_vector_type(8))) short short8;
typedef __attribute__((ext_vector_type(4))) unsigned short u16x4;
typedef __attribute__((ext_vector_type(4))) float f32x4;
typedef __attribute__((ext_vector_type(4))) int i32x4;

__device__ inline unsigned short bf16rne(float x) {
    unsigned u = __float_as_uint(x);
    unsigned r = (u + 0x7FFFu + ((u >> 16) & 1u)) >> 16;
    return (unsigned short)r;
}
__device__ inline float bf16tof(unsigned short h) {
    return __uint_as_float((unsigned)h << 16);
}
__device__ inline void gload16(const void* g, void* l) {
    __builtin_amdgcn_global_load_lds((const __attribute__((address_space(1))) void*)g,
                                     (__attribute__((address_space(3))) void*)l, 16, 0, 0);
}
// cross-lane add via DPP (VALU only, no DS crossbar). CTRL: 0xB1=quad_perm
// xor1, 0x4E=quad_perm xor2, 0x124=row_ror:4, 0x128=row_ror:8.
template <int CTRL>
__device__ inline float dpp_add(float x) {
    int v = __builtin_amdgcn_update_dpp(0, __float_as_int(x), CTRL, 0xF, 0xF, true);
    return x + __int_as_float(v);
}

// ---------- CSR build (4-aligned padded segments) ----------

__global__ __launch_bounds__(256) void k_deg(const int* __restrict__ ei, int* __restrict__ deg) {
    int e = blockIdx.x * 256 + threadIdx.x;
    if (e >= EPAD) return;
    int dst = (e < EE) ? ei[EE + e] : (e - EE);
    atomicAdd(&deg[dst], 1);
}

// log-depth scan (wave shfl_up + wave-total scan)
__global__ __launch_bounds__(1024) void k_scan(const int* __restrict__ deg, int* __restrict__ rowptr) {
    __shared__ int wsum[16];
    int t = threadIdx.x;
    int lane = t & 63, wid = t >> 6;
    int loc[8];
    int s = 0;
#pragma unroll
    for (int i = 0; i < 8; i++) { loc[i] = s; s += (deg[t * 8 + i] + 3) & ~3; }
    int inc = s;
#pragma unroll
    for (int off = 1; off < 64; off <<= 1) {
        int v = __shfl_up(inc, off);
        if (lane >= off) inc += v;
    }
    if (lane == 63) wsum[wid] = inc;
    __syncthreads();
    if (wid == 0 && lane < 16) {
        int v = wsum[lane];
#pragma unroll
        for (int off = 1; off < 16; off <<= 1) {
            int u = __shfl_up(v, off);
            if (lane >= off) v += u;
        }
        wsum[lane] = v;
    }
    __syncthreads();
    int wbase = (wid == 0) ? 0 : wsum[wid - 1];
    int base = wbase + inc - s;          // exclusive prefix for this thread
#pragma unroll
    for (int i = 0; i < 8; i++) rowptr[t * 8 + i] = base + loc[i];
    if (t == 1023) rowptr[NN] = wbase + inc;
}

__global__ __launch_bounds__(256) void k_scatter(const int* __restrict__ ei, const int* __restrict__ rowptr,
                                                 int* __restrict__ cursor, int* __restrict__ ssrc) {
    int e = blockIdx.x * 256 + threadIdx.x;
    if (e >= EPAD) return;
    int src = (e < EE) ? ei[e] : (e - EE);
    int dst = (e < EE) ? ei[EE + e] : (e - EE);
    int pos = rowptr[dst] + atomicAdd(&cursor[dst], 1);
    ssrc[pos] = src;
}

// fill pad slots with src=0 (row 0 gather, masked out of softmax)
__global__ __launch_bounds__(256) void k_pad(const int* __restrict__ rowptr, const int* __restrict__ deg,
                                             int* __restrict__ ssrc) {
    int n = blockIdx.x * 256 + threadIdx.x;
    if (n >= NN) return;
    int e = rowptr[n] + deg[n], pe = rowptr[n + 1];
    for (int i = e; i < pe; i++) ssrc[i] = 0;
}

// ---------- conversions ----------

__global__ __launch_bounds__(256) void k_cvt_ah(const float* __restrict__ F,
                                                unsigned short* __restrict__ Ah, int n4) {
    int i = blockIdx.x * 256 + threadIdx.x;
    if (i >= n4) return;
    f32x4 v = ((const f32x4*)F)[i];
#pragma unroll
    for (int c = 0; c < 4; c++) Ah[i * 4 + c] = bf16rne(v[c]);
}

// W[K][512] (Wl,Wr) -> Wt[n=1024][K] bf16-hi (transposed, K contiguous)
template <int K>
__global__ __launch_bounds__(256) void k_cvt_w(const float* __restrict__ Wl, const float* __restrict__ Wr,
                                               unsigned short* __restrict__ Wh) {
    int idx = blockIdx.x * 256 + threadIdx.x;   // = n*K + k
    int n = idx / K, k = idx % K;
    const float* W = (n < 512) ? Wl : Wr;
    Wh[idx] = bf16rne(W[k * 512 + (n & 511)]);
}

// ---------- bf16 MFMA GEMM: [NT x K] @ [K x 1024] -> XLb (bf16) | XR (f32) ----------
// Double-buffered LDS + COUNTED vmcnt via inline asm (catalog T4): stage
// next slab, s_waitcnt vmcnt(4) waits only the CURRENT slab's 4 loads
// (issued one slab earlier -> already landed under the MFMA work), raw
// s_barrier (no vmcnt(0) drain -- r13's __syncthreads failure mode).
// BK=32 keeps LDS at 32KB = 5 blocks/CU. sched_barrier(0) fences per
// rule #18 (hipcc hoists past inline-asm waitcnt otherwise).

#define STAGE(B, k0)                                                         \
  {                                                                          \
    _Pragma("unroll") for (int g = 0; g < 2; g++) {                          \
      int cell = g * 256 + tid;                                              \
      int ckh = cell >> 7, cr = cell & 127;                                  \
      int ka = (k0) + ckh * 8;                                               \
      gload16(Ah + (size_t)(m0 + cr) * K + ka, &sAh[B][ckh][cr][0]);         \
      gload16(Bh + (size_t)(n0 + cr) * K + ka, &sBh[B][ckh][cr][0]);         \
    }                                                                        \
  }

template <int K>
__global__ __launch_bounds__(256) void k_gemm_mfma(const unsigned short* __restrict__ Ah,
                                                   const unsigned short* __restrict__ Bh,
                                                   unsigned short* __restrict__ XLb,
                                                   float* __restrict__ XR) {
    __shared__ unsigned short sAh[2][4][128][8], sBh[2][4][128][8];
    int tid = threadIdx.x;
    int l = tid & 63;
    int w = tid >> 6, wm = w >> 1, wn = w & 1;
    int m0 = blockIdx.x * 128, n0 = blockIdx.y * 128;
    int lr = l & 15, kh = l >> 4;
    f32x4 acc[4][4] = {};

    STAGE(0, 0);                          // prologue: slab 0 in flight
    int buf = 0;
    for (int k0 = 0; k0 < K; k0 += 32) {
        if (k0 + 32 < K) {
            STAGE(buf ^ 1, k0 + 32);      // issue next slab (4 loads/thread)
            asm volatile("s_waitcnt vmcnt(4)" ::: "memory");  // wait CURRENT only
        } else {
            asm volatile("s_waitcnt vmcnt(0)" ::: "memory");
        }
        __builtin_amdgcn_sched_barrier(0);
        __builtin_amdgcn_s_barrier();     // all waves' current-slab loads landed
        __builtin_amdgcn_sched_barrier(0);
        short8 fah[4], fbh[4];
#pragma unroll
        for (int i = 0; i < 4; i++) {
            fah[i] = *(const short8*)&sAh[buf][kh][wm * 64 + i * 16 + lr][0];
            fbh[i] = *(const short8*)&sBh[buf][kh][wn * 64 + i * 16 + lr][0];
        }
#pragma unroll
        for (int i = 0; i < 4; i++)
#pragma unroll
            for (int j = 0; j < 4; j++)
                acc[i][j] = __builtin_amdgcn_mfma_f32_16x16x32_bf16(fah[i], fbh[j], acc[i][j], 0, 0, 0);
        __builtin_amdgcn_sched_barrier(0);
        __builtin_amdgcn_s_barrier();     // protect buf before next overwrite
        buf ^= 1;
    }
    // C/D layout: col = lane&15, row = (lane>>4)*4 + q  [m89-verified]
    int colt = n0 + wn * 64;     // wave-uniform
    int cb = colt & 511;
    if (colt < 512) {
#pragma unroll
        for (int i = 0; i < 4; i++) {
            int mg = m0 + wm * 64 + i * 16 + kh * 4;
#pragma unroll
            for (int j = 0; j < 4; j++) {
                int cg = cb + j * 16 + lr;
#pragma unroll
                for (int q = 0; q < 4; q++)
                    XLb[(size_t)(mg + q) * CH + cg] = bf16rne(acc[i][j][q]);
            }
        }
    } else {
#pragma unroll
        for (int i = 0; i < 4; i++) {
            int mg = m0 + wm * 64 + i * 16 + kh * 4;
#pragma unroll
            for (int j = 0; j < 4; j++) {
                int cg = cb + j * 16 + lr;
#pragma unroll
                for (int q = 0; q < 4; q++)
                    XR[(size_t)(mg + q) * CH + cg] = acc[i][j][q];
            }
        }
    }
}

// ---------- fused per-node: logits + online softmax + aggregation ----------
// r15 structure (node floor: 77% VALUBusy + random-gather L2-bound; ten
// variants tried, 63.6us invariant). 2 consecutive nids per 256-thread
// block; 2 waves per node (head-group g); lane l owns 4 consecutive
// channels g*256+l*4 (one head). 3-deep pipeline over 4-edge chunks.
// Single bf16->f32 convert per value; lrelu = max(t, 0.2t). DPP-only fold;
// per-lane softmax state; defer-rescale THR=8. Tail/pad masked via z=-1e30.

#define GATHER(CX, IV)                                                         \
  {                                                                            \
    CX[0] = *(const u16x4*)(XLg + (size_t)IV[0] * CH);                         \
    CX[1] = *(const u16x4*)(XLg + (size_t)IV[1] * CH);                         \
    CX[2] = *(const u16x4*)(XLg + (size_t)IV[2] * CH);                         \
    CX[3] = *(const u16x4*)(XLg + (size_t)IV[3] * CH);                         \
  }

#define PROCESS(CX, cb)                                                        \
  {                                                                            \
    float f[4][4];                                                             \
    _Pragma("unroll") for (int e = 0; e < 4; e++)                              \
      _Pragma("unroll") for (int r = 0; r < 4; r++)                            \
        f[e][r] = bf16tof(CX[e][r]);                                           \
    float z[4];                                                                \
    _Pragma("unroll") for (int e = 0; e < 4; e++) {                            \
      float s = 0.f;                                                           \
      _Pragma("unroll") for (int r = 0; r < 4; r++) {                          \
        float t = f[e][r] + xrv[r];                                            \
        t = fmaxf(t, NEG * t);                                                 \
        s += t * atv[r];                                                       \
      }                                                                        \
      z[e] = s;                                                                \
    }                                                                          \
    _Pragma("unroll") for (int e = 0; e < 4; e++) {                            \
      z[e] = dpp_add<0xB1>(z[e]);                                              \
      z[e] = dpp_add<0x4E>(z[e]);                                              \
      z[e] = dpp_add<0x124>(z[e]);                                             \
      z[e] = dpp_add<0x128>(z[e]);                                             \
    }                                                                          \
    _Pragma("unroll") for (int e = 1; e < 4; e++)                              \
      if ((cb) + e >= end) z[e] = -1e30f;                                      \
    float mc = fmaxf(fmaxf(z[0], z[1]), fmaxf(z[2], z[3]));                    \
    if (__ballot(mc > mh + 8.f) == 0ULL) {                                     \
      float p0 = __expf(z[0] - mh), p1 = __expf(z[1] - mh);                    \
      float p2 = __expf(z[2] - mh), p3 = __expf(z[3] - mh);                    \
      sh += (p0 + p1) + (p2 + p3);                                             \
      _Pragma("unroll") for (int r = 0; r < 4; r++)                            \
        acc[r] += p0 * f[0][r] + p1 * f[1][r] + p2 * f[2][r] + p3 * f[3][r];   \
    } else {                                                                   \
      float nm = fmaxf(mh, mc);                                                \
      float sc = __expf(mh - nm);                                              \
      float p0 = __expf(z[0] - nm), p1 = __expf(z[1] - nm);                    \
      float p2 = __expf(z[2] - nm), p3 = __expf(z[3] - nm);                    \
      sh = sh * sc + (p0 + p1) + (p2 + p3);                                    \
      mh = nm;                                                                 \
      _Pragma("unroll") for (int r = 0; r < 4; r++)                            \
        acc[r] = acc[r] * sc + p0 * f[0][r] + p1 * f[1][r] + p2 * f[2][r] +    \
                 p3 * f[3][r];                                                 \
    }                                                                          \
  }

template <int WRITE_BF16>
__global__ __launch_bounds__(256) void k_node5(const unsigned short* __restrict__ XLb,
                                               const float* __restrict__ XR,
                                               const int* __restrict__ rowptr,
                                               const int* __restrict__ deg,
                                               const int* __restrict__ ssrc,
                                               const float* __restrict__ att,
                                               const float* __restrict__ bias,
                                               float* __restrict__ OUT,
                                               unsigned short* __restrict__ OAh) {
    int w = threadIdx.x >> 6;
    int nid = blockIdx.x * 2 + (w >> 1);   // global row 0..NT-1
    int g = w & 1;                         // head-group: heads g*4 .. g*4+3
    int l = threadIdx.x & 63;
    int node = nid & (NN - 1);
    int beg = rowptr[node], pend = rowptr[node + 1];
    int end = beg + deg[node];
    int hb = g * 256 + l * 4;              // 4 consecutive channels, one head

    const unsigned short* XLg = XLb + (size_t)(nid >> 13) * NN * CH + hb;
    f32x4 xrv = *(const f32x4*)(XR + (size_t)nid * CH + hb);
    f32x4 atv = *(const f32x4*)(att + hb);
    f32x4 acc = {0.f, 0.f, 0.f, 0.f};
    float mh = -1e30f, sh = 0.f;

    i32x4 iA = *(const i32x4*)(ssrc + beg);
    i32x4 iB = iA;
    u16x4 curA[4], curB[4];
    GATHER(curA, iA);
    if (beg + 4 < pend) iB = *(const i32x4*)(ssrc + beg + 4);

    int base = beg;
    while (true) {
        // invariant: curA = data(c), iB = idx(c+1)
        if (base + 4 < pend) GATHER(curB, iB);
        if (base + 8 < pend) iA = *(const i32x4*)(ssrc + base + 8);
        PROCESS(curA, base);
        base += 4;
        if (base >= pend) break;
        // invariant: curB = data(c'), iA = idx(c'+1)
        if (base + 4 < pend) GATHER(curA, iA);
        if (base + 8 < pend) iB = *(const i32x4*)(ssrc + base + 8);
        PROCESS(curB, base);
        base += 4;
        if (base >= pend) break;
    }

    float inv = 1.f / sh;
    f32x4 biasv = *(const f32x4*)(bias + hb);
    size_t ob = (size_t)nid * CH + hb;
    if (WRITE_BF16) {
        u16x4 hv;
#pragma unroll
        for (int r = 0; r < 4; r++) {
            float wv = acc[r] * inv + biasv[r];
            hv[r] = bf16rne(wv);
        }
        *(u16x4*)(OAh + ob) = hv;
    } else {
        f32x4 ov;
#pragma unroll
        for (int r = 0; r < 4; r++) {
            float wv = acc[r] * inv + biasv[r];
            ov[r] = (wv > 0.f) ? wv : (__expf(wv) - 1.f);
        }
        *(f32x4*)(OUT + ob) = ov;
    }
}

// ---------- host ----------

extern "C" void kernel_launch(void* const* d_in, const int* in_sizes, int n_in,
                              void* d_out, int out_size, void* d_ws, size_t ws_size,
                              hipStream_t stream) {
    const float* x    = (const float*)d_in[0];
    const int*   ei   = (const int*)d_in[1];
    const float* W1l  = (const float*)d_in[2];
    const float* W1r  = (const float*)d_in[3];
    const float* att1 = (const float*)d_in[4];
    const float* b1   = (const float*)d_in[5];
    const float* W2l  = (const float*)d_in[6];
    const float* W2r  = (const float*)d_in[7];
    const float* att2 = (const float*)d_in[8];
    const float* b2   = (const float*)d_in[9];
    float* out = (float*)d_out;

    char* ws = (char*)d_ws;
    int* rowptr = (int*)ws;                 // NN+1
    int* cursor = rowptr + NN + 1;          // NN   (zeroed)
    int* deg    = cursor + NN;              // NN   (zeroed)
    int* ssrc   = deg + NN;                 // SPAD (4-aligned padded)
    unsigned short* XLb = (unsigned short*)(((uintptr_t)(ssrc + SPAD) + 255) & ~(uintptr_t)255);
    float* XR = (float*)(XLb + (size_t)NT * CH);
    unsigned short* A_h = (unsigned short*)(XR + (size_t)NT * CH);  // NT*CH bf16
    unsigned short* W1h = A_h + (size_t)NT * CH;   // 1024*FIN
    unsigned short* W2h = W1h + 1024 * FIN;        // 1024*CH

    hipMemsetAsync(cursor, 0, (size_t)2 * NN * sizeof(int), stream);
    k_deg<<<(EPAD + 255) / 256, 256, 0, stream>>>(ei, deg);
    k_scan<<<1, 1024, 0, stream>>>(deg, rowptr);
    k_scatter<<<(EPAD + 255) / 256, 256, 0, stream>>>(ei, rowptr, cursor, ssrc);
    k_pad<<<NN / 256, 256, 0, stream>>>(rowptr, deg, ssrc);
    k_cvt_w<FIN><<<1024 * FIN / 256, 256, 0, stream>>>(W1l, W1r, W1h);
    k_cvt_w<CH><<<1024 * CH / 256, 256, 0, stream>>>(W2l, W2r, W2h);

    // layer 1 (both batches merged: NT rows)
    k_cvt_ah<<<NT * FIN / 4 / 256, 256, 0, stream>>>(x, A_h, NT * FIN / 4);
    k_gemm_mfma<FIN><<<dim3(NT / 128, 8), 256, 0, stream>>>(A_h, W1h, XLb, XR);
    k_node5<1><<<NT / 2, 256, 0, stream>>>(XLb, XR, rowptr, deg, ssrc, att1, b1, nullptr, A_h);
    // layer 2
    k_gemm_mfma<CH><<<dim3(NT / 128, 8), 256, 0, stream>>>(A_h, W2h, XLb, XR);
    k_node5<0><<<NT / 2, 256, 0, stream>>>(XLb, XR, rowptr, deg, ssrc, att2, b2, out, nullptr);
}